// Round 10
// baseline (24722.002 us; speedup 1.0000x reference)
//
#include <hip/hip_runtime.h>
#include <stdint.h>

#define BB 64
#define TT 1024
#define EE 256
#define HH 512
#define NTAG 16

// ws 32-bit-unit layout:
//   h_pk [2 ring][2 dir][64 b][512 j] u32 (bf16 hi|lo packed) = 131072
//   flags at 131072: 8 groups x 32 producers x 32-int stride = 8192
//   e_f [64][1024][16] f32 at 139264 ; e_b after
#define HPK_OFF  0
#define FLAG_OFF 131072
#define EF_OFF   139264
#define EB_OFF   (EF_OFF + 1048576)

typedef short bf16x8 __attribute__((ext_vector_type(8)));
typedef float f32x4 __attribute__((ext_vector_type(4)));

__device__ __forceinline__ float sigm(float v) { return 1.0f / (1.0f + __expf(-v)); }
__device__ __forceinline__ float tanh_f(float v) { return 1.0f - 2.0f / (__expf(2.0f * v) + 1.0f); }

__device__ __forceinline__ unsigned bf16_rne(float f) {
  unsigned x = __float_as_uint(f);
  return (x + 0x7fffu + ((x >> 16) & 1u)) >> 16;
}
__device__ __forceinline__ void split_bf16(float f, unsigned& hi, unsigned& lo) {
  hi = bf16_rne(f);
  lo = bf16_rne(f - __uint_as_float(hi << 16));
}
__device__ __forceinline__ unsigned pack_hl(float f) {
  unsigned hi, lo; split_bf16(f, hi, lo);
  return (hi << 16) | lo;
}

template <int CTRL>
__device__ __forceinline__ float dpp_mov(float v) {
  int d = __builtin_amdgcn_update_dpp(0, __float_as_int(v), CTRL, 0xF, 0xF, true);
  return __int_as_float(d);
}
template <int CTRL>
__device__ __forceinline__ float dpp_add(float v) { return v + dpp_mov<CTRL>(v); }
// Sum across each 16-lane row (VALU-pipe DPP).
__device__ __forceinline__ float row16_reduce(float v) {
  v = dpp_add<0xB1>(v);    // quad_perm xor1
  v = dpp_add<0x4E>(v);    // quad_perm xor2
  v = dpp_add<0x124>(v);   // row_ror:4
  v = dpp_add<0x128>(v);   // row_ror:8
  return v;
}

__global__ void init_ws_kernel(unsigned* ws) {
  int i = blockIdx.x * blockDim.x + threadIdx.x;
  if (i < EF_OFF) ws[i] = 0u;  // zeros h_pk ring (packed 0 == 0.0f) + flags
}

// Persistent BiLSTM, MFMA recurrence (split-bf16, 3-term), proven R8 comms:
//  - 256 blocks x 256 threads (1/CU). group = bid&7 (dir x batch-quarter,
//    XCD-aligned); jsl = bid>>3 (32 j-slices of 16 hidden units).
//  - W_hh B-fragments (hi/lo bf16) resident in 128 VGPRs per lane: no LDS, no
//    per-step W traffic. w_fc fragments split to 32KB LDS once.
//  - h exchanged as PACKED u32 (bf16 hi|lo) via sc1 relaxed atomics + the R8
//    per-producer flag protocol (no fences, L2 stays warm).
//  - x-part (emb/W_ih, L2-latency-bound) keeps proven acc[8][8]+DPP form and
//    merges into the MFMA accumulator via a 4KB LDS buffer (seed = xacc+bias).
//  - MFMA: each wave owns 16 gate-cols; per K-chunk: A-frags built from 8 sc1
//    u32 loads (k-indexing consistent A/B so any k-permutation cancels);
//    gates = 3 MFMAs/chunk. Wave 0 adds 3 more for emissions (same A-frags).
//  - Nonlinearity: gates live per-quad (col&3 = gate type); quad_perm DPP
//    broadcasts i,f,g,o; fp32 h/c carried exactly; lane col%4==0 stores h_pk.
__global__ void __launch_bounds__(256, 1)
lstm_kernel(const int* __restrict__ x, const float* __restrict__ emb,
            const float* __restrict__ w_ih_f, const float* __restrict__ w_hh_f,
            const float* __restrict__ b_f,
            const float* __restrict__ w_ih_b, const float* __restrict__ w_hh_b,
            const float* __restrict__ b_b,
            const float* __restrict__ w_fc, const float* __restrict__ b_fc,
            unsigned* __restrict__ ws)
{
  __shared__ __align__(16) short wfchi[8192];   // 16KB: w_fc hi frags [c][lane][8]
  __shared__ __align__(16) short wfclo[8192];   // 16KB: w_fc lo frags
  __shared__ __align__(16) float xacc[1024];    // 4KB: x-projection [16 b][64 r]

  const int tid = threadIdx.x;
  const int bid = blockIdx.x;
  const int group = bid & 7;
  const int jsl   = bid >> 3;            // 0..31
  const int dir   = group >> 2;
  const int bq    = group & 3;
  // x-part decomposition (proven)
  const int kc  = tid & 15;
  const int grp = tid >> 4;
  const int bg  = grp >> 3, grg = grp & 7;
  // MFMA decomposition
  const int wv   = tid >> 6;             // wave 0..3 owns gate-cols wv*16..+16
  const int ln   = tid & 63;
  const int col  = ln & 15;              // N-col in tile
  const int krow = ln >> 4;              // k-group (A/B), row-group (C/D)

  const float* w_ih = dir ? w_ih_b : w_ih_f;
  const float* w_hh = dir ? w_hh_b : w_hh_f;
  const float* bias = dir ? b_b : b_f;

  unsigned* h_pk = ws + HPK_OFF;
  int* gflags = (int*)ws + FLAG_OFF + group * 1024;
  float* earr = (float*)ws + (dir ? EB_OFF : EF_OFF);

  // ---- W_hh fragments (hi/lo) into registers, once ----
  const int rg    = wv * 16 + col;                       // gate-row 0..63 (r&3 = gate = ln&3)
  const int growW = (rg & 3) * 512 + jsl * 16 + (rg >> 2);
  bf16x8 whh_hi[16], whh_lo[16];
  #pragma unroll
  for (int c = 0; c < 16; ++c) {
    const float* src = w_hh + (size_t)growW * 512 + c * 32 + krow * 8;
    bf16x8 h8, l8;
    #pragma unroll
    for (int e = 0; e < 8; ++e) {
      unsigned hi, lo; split_bf16(src[e], hi, lo);
      h8[e] = (short)hi; l8[e] = (short)lo;
    }
    whh_hi[c] = h8; whh_lo[c] = l8;
  }

  // ---- w_fc fragments into LDS, once (B-frag: col=tag, same k-indexing) ----
  for (int q = 0; q < 4; ++q) {
    int f = tid * 4 + q;                 // frag id 0..1023
    int c = f >> 6, fl = f & 63;
    const float* src = w_fc + (size_t)(fl & 15) * 1024 + dir * 512 + c * 32 + (fl >> 4) * 8;
    #pragma unroll
    for (int e = 0; e < 8; ++e) {
      unsigned hi, lo; split_bf16(src[e], hi, lo);
      wfchi[f * 8 + e] = (short)hi;
      wfclo[f * 8 + e] = (short)lo;
    }
  }

  // x-part W_ih row pointers (8 gate-rows: jloc=grg*2+(r>>2), gate=r&3)
  const float4* wihp[8];
  #pragma unroll
  for (int r = 0; r < 8; ++r) {
    int gate = r & 3, jloc = grg * 2 + (r >> 2);
    wihp[r] = (const float4*)(w_ih + (size_t)(gate * 512 + jsl * 16 + jloc) * 256);
  }

  // MFMA epilogue constants
  const float biasl = bias[(ln & 3) * 512 + jsl * 16 + wv * 4 + (col >> 2)];
  const float bfc_l = b_fc[col];
  const int   j_out = jsl * 16 + wv * 4 + (col >> 2);
  float h_st[4] = {0.f, 0.f, 0.f, 0.f}, c_st[4] = {0.f, 0.f, 0.f, 0.f};
  bool dead = false;
  __syncthreads();                       // wfc LDS staged

  for (int s = 0; s <= TT; ++s) {
    const bool last = (s == TT);
    const int t = dir ? (TT - 1 - s) : s;

    // ---- x-part (L2-hot, off inter-block critical path) ----
    if (!last) {
      float acc[8][8];
      #pragma unroll
      for (int a = 0; a < 8; ++a)
        #pragma unroll
        for (int r = 0; r < 8; ++r) acc[a][r] = 0.0f;
      int xtok[8];
      #pragma unroll
      for (int b2 = 0; b2 < 8; ++b2)
        xtok[b2] = x[(size_t)(bq * 16 + bg * 8 + b2) * TT + t];
      #pragma unroll
      for (int i = 0; i < 4; ++i) {
        float4 wvv[8];
        #pragma unroll
        for (int r = 0; r < 8; ++r) wvv[r] = wihp[r][i * 16 + kc];
        #pragma unroll
        for (int b2 = 0; b2 < 8; ++b2) {
          float4 ev = ((const float4*)(emb + (size_t)xtok[b2] * EE))[i * 16 + kc];
          #pragma unroll
          for (int r = 0; r < 8; ++r) {
            acc[b2][r] = fmaf(ev.x, wvv[r].x, acc[b2][r]);
            acc[b2][r] = fmaf(ev.y, wvv[r].y, acc[b2][r]);
            acc[b2][r] = fmaf(ev.z, wvv[r].z, acc[b2][r]);
            acc[b2][r] = fmaf(ev.w, wvv[r].w, acc[b2][r]);
          }
        }
      }
      #pragma unroll
      for (int a = 0; a < 8; ++a)
        #pragma unroll
        for (int r = 0; r < 8; ++r) acc[a][r] = row16_reduce(acc[a][r]);

      float g0, g1, g2, g3;
      #define EXTRACT(K) case K: \
        g0 = acc[(K) & 7][((K) >> 3) * 4 + 0]; g1 = acc[(K) & 7][((K) >> 3) * 4 + 1]; \
        g2 = acc[(K) & 7][((K) >> 3) * 4 + 2]; g3 = acc[(K) & 7][((K) >> 3) * 4 + 3]; break;
      switch (kc) {
        EXTRACT(0) EXTRACT(1) EXTRACT(2) EXTRACT(3)
        EXTRACT(4) EXTRACT(5) EXTRACT(6) EXTRACT(7)
        EXTRACT(8) EXTRACT(9) EXTRACT(10) EXTRACT(11)
        EXTRACT(12) EXTRACT(13) EXTRACT(14)
        default: g0 = acc[7][4]; g1 = acc[7][5]; g2 = acc[7][6]; g3 = acc[7][7]; break;
      }
      #undef EXTRACT
      float4 gv4; gv4.x = g0; gv4.y = g1; gv4.z = g2; gv4.w = g3;
      *(float4*)&xacc[(bg * 8 + (kc & 7)) * 64 + (grg * 2 + (kc >> 3)) * 4] = gv4;
    }

    // ---- flag-wait: all 32 group producers published step s (no fence) ----
    if (tid < 64 && !dead) {
      bool ok = (tid >= 32);
      if (!ok)
        ok = (__hip_atomic_load(gflags + tid * 32, __ATOMIC_RELAXED,
                                __HIP_MEMORY_SCOPE_AGENT) >= s);
      long long deadline = clock64() + (1LL << 23);  // ~3.5ms budget PER WAIT
      int itc = 0;
      while (!__all(ok)) {
        __builtin_amdgcn_s_sleep(1);
        if (!ok)
          ok = (__hip_atomic_load(gflags + tid * 32, __ATOMIC_RELAXED,
                                  __HIP_MEMORY_SCOPE_AGENT) >= s);
        if (((++itc) & 15) == 0 && clock64() > deadline) { dead = true; break; }
      }
    }
    __syncthreads();                     // flags seen + xacc visible

    // ---- MFMA phase ----
    f32x4 gacc = {0.f, 0.f, 0.f, 0.f};
    f32x4 eacc = {0.f, 0.f, 0.f, 0.f};
    int xq[4];
    if (!last) {
      #pragma unroll
      for (int reg = 0; reg < 4; ++reg) {
        gacc[reg] = xacc[(krow * 4 + reg) * 64 + wv * 16 + col] + biasl;
        xq[reg] = x[(size_t)(bq * 16 + krow * 4 + reg) * TT + t];
      }
    }
    const bool do_em = (wv == 0) && (s >= 1);
    if (!last || do_em) {
      const unsigned* hrow =
          h_pk + ((size_t)((s & 1) * 2 + dir) * BB + bq * 16 + col) * HH;
      #pragma unroll
      for (int c = 0; c < 16; ++c) {
        const unsigned* p = hrow + c * 32 + krow * 8;
        unsigned u[8];
        #pragma unroll
        for (int e = 0; e < 8; ++e)
          u[e] = __hip_atomic_load(p + e, __ATOMIC_RELAXED, __HIP_MEMORY_SCOPE_AGENT);
        bf16x8 ahi, alo;
        #pragma unroll
        for (int e = 0; e < 8; ++e) {
          ahi[e] = (short)(u[e] >> 16);
          alo[e] = (short)(u[e] & 0xffffu);
        }
        if (!last) {
          gacc = __builtin_amdgcn_mfma_f32_16x16x32_bf16(ahi, whh_hi[c], gacc, 0, 0, 0);
          gacc = __builtin_amdgcn_mfma_f32_16x16x32_bf16(ahi, whh_lo[c], gacc, 0, 0, 0);
          gacc = __builtin_amdgcn_mfma_f32_16x16x32_bf16(alo, whh_hi[c], gacc, 0, 0, 0);
        }
        if (do_em) {
          bf16x8 bh  = *(const bf16x8*)&wfchi[(c * 64 + ln) * 8];
          bf16x8 bl8 = *(const bf16x8*)&wfclo[(c * 64 + ln) * 8];
          eacc = __builtin_amdgcn_mfma_f32_16x16x32_bf16(ahi, bh, eacc, 0, 0, 0);
          eacc = __builtin_amdgcn_mfma_f32_16x16x32_bf16(ahi, bl8, eacc, 0, 0, 0);
          eacc = __builtin_amdgcn_mfma_f32_16x16x32_bf16(alo, bh, eacc, 0, 0, 0);
        }
      }
    }

    // ---- gate epilogue: quad DPP gather -> nonlin -> packed h store ----
    if (!last) {
      unsigned* h_pk_w = h_pk + (size_t)(((s + 1) & 1) * 2 + dir) * BB * HH;
      #pragma unroll
      for (int reg = 0; reg < 4; ++reg) {
        float gvv = gacc[reg];
        float gi = dpp_mov<0x00>(gvv), gf = dpp_mov<0x55>(gvv);
        float gg = dpp_mov<0xAA>(gvv), go = dpp_mov<0xFF>(gvv);
        float iv = sigm(gi), fv = sigm(gf), gg2 = tanh_f(gg), ov = sigm(go);
        float cn = fmaf(fv, c_st[reg], iv * gg2);
        float hn = ov * tanh_f(cn);
        bool mv = (xq[reg] != 0);
        float h2 = mv ? hn : h_st[reg];
        float c2 = mv ? cn : c_st[reg];
        h_st[reg] = h2; c_st[reg] = c2;
        if ((ln & 3) == 0)
          __hip_atomic_store(
              h_pk_w + (size_t)(bq * 16 + krow * 4 + reg) * HH + j_out,
              pack_hl(h2), __ATOMIC_RELAXED, __HIP_MEMORY_SCOPE_AGENT);
      }
    }

    // ---- emission epilogue (wave 0) ----
    if (do_em) {
      int t_prev = dir ? (TT - s) : (s - 1);
      #pragma unroll
      for (int reg = 0; reg < 4; ++reg) {
        int b = bq * 16 + krow * 4 + reg;
        int mm = (x[(size_t)b * TT + t_prev] != 0);
        float e = mm ? eacc[reg] : 0.0f;
        if (dir == 0) e += bfc_l;
        earr[((size_t)b * TT + t_prev) * NTAG + col] = e;
      }
    }

    __syncthreads();                     // all sc1 h stores drained (vmcnt 0)
    if (!last && tid == 0)
      __hip_atomic_store(gflags + jsl * 32, s + 1, __ATOMIC_RELEASE,
                         __HIP_MEMORY_SCOPE_AGENT);   // parallel publish
  }
}

// Viterbi: one block (1 wave) per batch row. Lanes replicate j = lane&15.
__global__ void __launch_bounds__(64)
vit_kernel(const int* __restrict__ x, const float* __restrict__ trans,
           const float* __restrict__ ws, float* __restrict__ out)
{
  const int b = blockIdx.x;
  const int lane = threadIdx.x;
  const int j = lane & 15;
  const float* ef = ws + EF_OFF;
  const float* eb = ws + EB_OFF;

  __shared__ unsigned long long bp[TT];
  __shared__ int pathl[TT];

  float tcol[16];
  #pragma unroll
  for (int i = 0; i < 16; ++i) tcol[i] = trans[i * 16 + j];
  const float teos = trans[j * 16 + 2];

  float alpha = trans[1 * 16 + j]
              + ef[((size_t)b * TT + 0) * NTAG + j] + eb[((size_t)b * TT + 0) * NTAG + j];

  float ecur = ef[((size_t)b * TT + 1) * NTAG + j] + eb[((size_t)b * TT + 1) * NTAG + j];
  int mcur = (x[b * TT + 1] != 0);

  for (int t = 1; t < TT; ++t) {
    float enext = 0.0f; int mnext = 0;
    if (t + 1 < TT) {
      enext = ef[((size_t)b * TT + t + 1) * NTAG + j] + eb[((size_t)b * TT + t + 1) * NTAG + j];
      mnext = (x[b * TT + t + 1] != 0);
    }
    float best = -3.0e38f; int arg = 0;
    #pragma unroll
    for (int i = 0; i < 16; ++i) {
      float ai = __shfl(alpha, i);
      float sc = ai + tcol[i];
      if (sc > best) { best = sc; arg = i; }  // strict > => first max (jnp.argmax)
    }
    float an = best + ecur;
    int bpj = mcur ? arg : j;
    alpha = mcur ? an : alpha;
    unsigned long long nib = (unsigned long long)(bpj & 15) << (4 * j);
    #pragma unroll
    for (int d = 1; d < 16; d <<= 1) nib |= __shfl_xor(nib, d);
    if (lane == 0) bp[t] = nib;
    ecur = enext; mcur = mnext;
  }

  float endv = alpha + teos;
  int bi = j;
  #pragma unroll
  for (int d = 1; d < 64; d <<= 1) {
    float ov = __shfl_xor(endv, d);
    int oi = __shfl_xor(bi, d);
    if (ov > endv || (ov == endv && oi < bi)) { endv = ov; bi = oi; }
  }

  if (lane == 0) {
    out[b] = endv;
    int tag = bi;
    pathl[TT - 1] = tag;
    for (int t = TT - 1; t >= 1; --t) {
      tag = (int)((bp[t] >> (4 * tag)) & 15ull);
      pathl[t - 1] = tag;
    }
  }
  __syncthreads();
  for (int t = lane; t < TT; t += 64) {
    int mm = (x[b * TT + t] != 0);
    out[64 + (size_t)b * TT + t] = mm ? (float)pathl[t] : 0.0f;
  }
}

extern "C" void kernel_launch(void* const* d_in, const int* in_sizes, int n_in,
                              void* d_out, int out_size, void* d_ws, size_t ws_size,
                              hipStream_t stream) {
  (void)in_sizes; (void)n_in; (void)out_size; (void)ws_size;
  const int*   x    = (const int*)d_in[0];
  const float* emb  = (const float*)d_in[1];
  const float* wihf = (const float*)d_in[2];
  const float* whhf = (const float*)d_in[3];
  const float* bf   = (const float*)d_in[4];
  const float* wihb = (const float*)d_in[5];
  const float* whhb = (const float*)d_in[6];
  const float* bb   = (const float*)d_in[7];
  const float* wfc  = (const float*)d_in[8];
  const float* bfc  = (const float*)d_in[9];
  const float* tr   = (const float*)d_in[10];
  unsigned* ws = (unsigned*)d_ws;
  float* out = (float*)d_out;

  hipLaunchKernelGGL(init_ws_kernel, dim3(544), dim3(256), 0, stream, ws);
  hipLaunchKernelGGL(lstm_kernel, dim3(256), dim3(256), 0, stream,
                     x, emb, wihf, whhf, bf, wihb, whhb, bb, wfc, bfc, ws);
  hipLaunchKernelGGL(vit_kernel, dim3(64), dim3(64), 0, stream,
                     x, tr, (const float*)ws, out);
}